// Round 15
// baseline (814.661 us; speedup 1.0000x reference)
//
#include <hip/hip_runtime.h>

#define NSEQ 576
#define CDIM 256
#define HEADS 3
#define HD 64
#define FEAT 192      // HEADS*HD
#define QKVF 576      // 3*FEAT
#define QK_F 384      // stored q,k cols
#define VP 70         // HD+6
#define BHN 192       // 64*3
#define DIMSZ 29400   // 2*3*70*70

typedef __attribute__((ext_vector_type(8))) _Float16 half8;
typedef __attribute__((ext_vector_type(4))) _Float16 half4;
typedef __attribute__((ext_vector_type(4))) float f32x4;

#define MFMA16(A,B,C) __builtin_amdgcn_mfma_f32_16x16x32_f16(A,B,C,0,0,0)

// positional encoding: pos[n] = {py^2, px^2, py*px, py, px, 1}
__device__ __forceinline__ float posval(int n, int pe){
  int yi = n % 24, xi = n / 24;
  float py = (float)yi * (2.0f/23.0f) - 1.0f;
  float px = (float)xi * (2.0f/23.0f) - 1.0f;
  switch(pe){
    case 0: return py*py;
    case 1: return px*px;
    case 2: return py*px;
    case 3: return py;
    case 4: return px;
    default: return 1.0f;
  }
}

// MFMA fragment, k-enum kappa(hi,i) = dbase + (i>>2)*16 + (i&3); LD = row stride
template<int LD>
__device__ __forceinline__ half8 fragT(const _Float16 (*s)[LD], int row, int dbase){
  half4 a = *(const half4*)&s[row][dbase];
  half4 b = *(const half4*)&s[row][dbase + 16];
  return __builtin_shufflevector(a, b, 0, 1, 2, 3, 4, 5, 6, 7);
}

// copy 64 rows x 64 cols of f16 from global (row stride rstr halfs) into LDS [64][72]
__device__ __forceinline__ void stage_copy64(const _Float16* __restrict__ src, int rstr,
                                             _Float16 (*d)[72], int t){
  #pragma unroll
  for (int k2 = 0; k2 < 2; ++k2){
    int idx = t + 256 * k2;               // 512 chunks of 8 halfs
    int row = idx >> 3, c = (idx & 7) << 3;
    half8 v = *(const half8*)(src + (size_t)row * rstr + c);
    *(half4*)&d[row][c]     = (half4){v[0], v[1], v[2], v[3]};
    *(half4*)&d[row][c + 4] = (half4){v[4], v[5], v[6], v[7]};
  }
}

// Rotated 64-col tile addressing (halfs): row stride 64, 16B-chunk rotation.
__device__ __forceinline__ int rotIdx(int row, int c16){
  return row * 64 + ((((c16) + row) & 7) << 3);
}

// ---- K0: LayerNorm stats
__global__ __launch_bounds__(192) void k_ln_stats(const float* __restrict__ x1, const float* __restrict__ x2,
                                                  float* __restrict__ mu, float* __restrict__ rstd){
  int idx = blockIdx.x;                 // 384
  int i2 = idx / 192;
  int rem = idx % 192;
  int b = rem / 3, ng = rem % 3;
  int n = ng * 192 + threadIdx.x;
  const float* x = i2 ? x2 : x1;
  const float* xb = x + (size_t)b * CDIM * NSEQ + n;
  float s = 0.f, sq = 0.f;
  for (int c = 0; c < CDIM; ++c){
    float v = xb[(size_t)c * NSEQ];
    s += v; sq += v * v;
  }
  float m = s * (1.0f/256.0f);
  float var = sq * (1.0f/256.0f) - m * m;
  int o = (i2 * 64 + b) * NSEQ + n;
  mu[o] = m;
  rstd[o] = rsqrtf(var + 1e-5f);
}

// ---- K0b: repack qkv_w into fragment-order split-f16 chunks (R13, validated).
__global__ __launch_bounds__(256) void k_w_repack(const float* __restrict__ qkvw,
                                                  _Float16* __restrict__ wrh, _Float16* __restrict__ wrl){
  int idx = blockIdx.x * 256 + threadIdx.x;   // 18432 chunks
  if (idx >= 18432) return;
  int fi = idx & 63;
  int r = idx >> 6;
  int hi = r & 3; r >>= 2;
  int kc = r & 1; r >>= 1;
  int cb = r & 3; r >>= 2;
  int ft = r;                 // 0..8
  int f = ft * 64 + fi;
  int cbase = cb * 64 + kc * 32 + hi * 4;
  const float* src = qkvw + (size_t)f * CDIM + cbase;
  float4 a = *(const float4*)src;
  float4 b = *(const float4*)(src + 16);
  float vv[8] = {a.x, a.y, a.z, a.w, b.x, b.y, b.z, b.w};
  half8 h, l;
  #pragma unroll
  for (int j = 0; j < 8; ++j){
    _Float16 hh = (_Float16)vv[j];
    h[j] = hh;
    l[j] = (_Float16)(vv[j] - (float)hh);
  }
  *(half8*)(wrh + (size_t)idx * 8) = h;
  *(half8*)(wrl + (size_t)idx * 8) = l;
}

// ---- K1: fused LN + QKV GEMM (R13 version, validated)
__global__ __launch_bounds__(256) void k_qkv_gemm_mfma(const float* __restrict__ x1, const float* __restrict__ x2,
                                                       const float* __restrict__ mu, const float* __restrict__ rstd,
                                                       const float* __restrict__ lnw, const float* __restrict__ lnb,
                                                       const _Float16* __restrict__ wrh, const _Float16* __restrict__ wrl,
                                                       _Float16* __restrict__ qh, _Float16* __restrict__ ql,
                                                       _Float16* __restrict__ vpTh, _Float16* __restrict__ vpTl){
  int wg = (blockIdx.x & 7) * 1296 + (blockIdx.x >> 3);   // 10368 = 8*1296
  int ft = wg % 9;
  int mt = wg / 9;
  int ibn = mt * 64;
  int i2 = ibn / (64 * NSEQ);
  int bn = ibn % (64 * NSEQ);
  int b  = bn / NSEQ;
  int n0 = bn % NSEQ;
  const float* x = i2 ? x2 : x1;
  const float* xb = x + (size_t)b * CDIM * NSEQ + n0;
  __shared__ __align__(16) _Float16 Xh[64][68];
  __shared__ __align__(16) _Float16 Xl[64][68];
  __shared__ float smu[64], srstd[64], slnw[256], slnb[256];
  int t = threadIdx.x;
  int w = t >> 6, lane = t & 63, tx = lane & 15, hi = lane >> 4;
  if (t < 64){ smu[t] = mu[ibn + t]; srstd[t] = rstd[ibn + t]; }
  slnw[t] = lnw[t]; slnb[t] = lnb[t];

  f32x4 acc[4];
  #pragma unroll
  for (int s = 0; s < 4; ++s) acc[s] = (f32x4){0.f, 0.f, 0.f, 0.f};

  int nA = t & 63, cg = t >> 6;
  int lchunk = hi * 64 + w * 16 + tx;
  for (int c0 = 0; c0 < CDIM; c0 += 64){
    int cb = c0 >> 6;
    __syncthreads();
    float mun = smu[nA], rsn = srstd[nA];
    #pragma unroll
    for (int rr = 0; rr < 16; ++rr){
      int c = cg * 16 + rr;
      float v = xb[(size_t)(c0 + c) * NSEQ + nA];
      float xv = (v - mun) * rsn * slnw[c0 + c] + slnb[c0 + c];
      _Float16 hh = (_Float16)xv;
      Xh[nA][c] = hh;
      Xl[nA][c] = (_Float16)(xv - (float)hh);
    }
    __syncthreads();
    #pragma unroll
    for (int kc = 0; kc < 2; ++kc){
      size_t wo = ((size_t)((ft * 4 + cb) * 2 + kc) * 256 + lchunk) * 8;
      half8 wh = *(const half8*)(wrh + wo);
      half8 wl = *(const half8*)(wrl + wo);
      #pragma unroll
      for (int s = 0; s < 4; ++s){
        half8 xh = fragT<68>(Xh, s * 16 + tx, kc * 32 + hi * 4);
        half8 xl = fragT<68>(Xl, s * 16 + tx, kc * 32 + hi * 4);
        acc[s] = MFMA16(xh, wh, acc[s]);
        acc[s] = MFMA16(xl, wh, acc[s]);
        acc[s] = MFMA16(xh, wl, acc[s]);
      }
    }
  }
  if (ft < 6){
    #pragma unroll
    for (int s = 0; s < 4; ++s)
      #pragma unroll
      for (int rr = 0; rr < 4; ++rr){
        float v = acc[s][rr];
        _Float16 hh = (_Float16)v;
        size_t o = (size_t)(ibn + s * 16 + hi * 4 + rr) * QK_F + ft * 64 + w * 16 + tx;
        qh[o] = hh;
        ql[o] = (_Float16)(v - (float)hh);
      }
  } else {
    __syncthreads();
    #pragma unroll
    for (int s = 0; s < 4; ++s)
      #pragma unroll
      for (int rr = 0; rr < 4; ++rr){
        float v = acc[s][rr];
        _Float16 hh = (_Float16)v;
        Xh[s * 16 + hi * 4 + rr][w * 16 + tx] = hh;
        Xl[s * 16 + hi * 4 + rr][w * 16 + tx] = (_Float16)(v - (float)hh);
      }
    __syncthreads();
    int mbg = i2 * 192 + b * 3 + (ft - 6);
    #pragma unroll
    for (int it = 0; it < 16; ++it){
      int d = (t >> 6) + it * 4;
      int n2 = t & 63;
      size_t o = ((size_t)mbg * 80 + d) * NSEQ + n0 + n2;
      vpTh[o] = Xh[n2][d];
      vpTl[o] = Xl[n2][d];
    }
  }
}

// ---- K1b: fill vpT positional rows 64..79 (rows 70..79 zero)
__global__ __launch_bounds__(256) void k_pos_fill(_Float16* __restrict__ vpTh, _Float16* __restrict__ vpTl){
  int idx = blockIdx.x * 256 + threadIdx.x;
  if (idx >= 384 * 16 * NSEQ) return;
  int n = idx % NSEQ;
  int r = idx / NSEQ;
  int row = 64 + (r & 15);
  int mb = r >> 4;
  float v = 0.f;
  int pe = row - 64;
  if (pe < 6) v = posval(n, pe);
  _Float16 hh = (_Float16)v;
  size_t o = ((size_t)mb * 80 + row) * NSEQ + n;
  vpTh[o] = hh;
  vpTl[o] = (_Float16)(v - (float)hh);
}

// ---- K2: attention stats v7 — barrier-free main loop. Each wave owns a private
// 144-row m-range (9 slices of 16) staged into its own 2KB LDS region with
// T14 reg-prefetch; intra-wave write->read ordering via compiler waitcnts only.
// Math identical to R13/R14 (same k-enum, exp, reductions).
__global__ __launch_bounds__(256, 4) void k_attn_stats_mfma(const _Float16* __restrict__ qh, const _Float16* __restrict__ ql,
                                                            float* __restrict__ rs, float* __restrict__ cs_part){
  int wg = (blockIdx.x & 7) * 432 + (blockIdx.x >> 3);   // 3456 = 8*432
  int map = wg / (BHN * 9);
  int r   = wg % (BHN * 9);
  int bh = r / 9, nt = r % 9;
  int b = bh / 3, h = bh % 3;
  int qi = 1 - map, ki = map;
  int mb = map * BHN + bh;
  const _Float16* qbh = qh + (size_t)((qi * 64 + b) * NSEQ) * QK_F + h * HD;
  const _Float16* qbl = ql + (size_t)((qi * 64 + b) * NSEQ) * QK_F + h * HD;
  const _Float16* kbh = qh + (size_t)((ki * 64 + b) * NSEQ) * QK_F + FEAT + h * HD;
  const _Float16* kbl = ql + (size_t)((ki * 64 + b) * NSEQ) * QK_F + FEAT + h * HD;
  int n0 = nt * 64;
  __shared__ __align__(16) _Float16 Sh[4096];    // Q stage, then 4x wave-private K
  __shared__ __align__(16) _Float16 Sl[4096];
  __shared__ float rsLds[4][64];
  int t = threadIdx.x;
  int w = t >> 6, lane = t & 63, tx = lane & 15, hi = lane >> 4;

  // stage Q (rows n0..n0+63) rotated, extract persistent A-frags
  for (int idx = t; idx < 1024; idx += 256){
    int a = idx >> 9, rc = idx & 511, row = rc >> 3, c16 = rc & 7;
    const _Float16* src = a ? qbl : qbh;
    _Float16* dst = a ? Sl : Sh;
    *(half8*)(dst + rotIdx(row, c16)) = *(const half8*)(src + (size_t)(n0 + row) * QK_F + c16 * 8);
  }
  __syncthreads();
  half8 qAh[4][2], qAl[4][2];
  #pragma unroll
  for (int s = 0; s < 4; ++s)
    #pragma unroll
    for (int kc = 0; kc < 2; ++kc){
      qAh[s][kc] = *(half8*)(Sh + rotIdx(s * 16 + tx, kc * 4 + hi));
      qAl[s][kc] = *(half8*)(Sl + rotIdx(s * 16 + tx, kc * 4 + hi));
    }
  __syncthreads();                    // all Q reads done; regions become private

  // wave-private K region (16 rows x 64 cols, rotated within 16-row tile)
  _Float16* kh = Sh + w * 1024;
  _Float16* kl = Sl + w * 1024;
  int mw0 = w * 144;
  half8 kPh[2], kPl[2];
  auto loadK = [&](int i){
    int m0r = mw0 + i * 16;
    #pragma unroll
    for (int p = 0; p < 2; ++p){
      int ch = p * 64 + lane;         // 128 chunks: row = ch>>3, c16 = ch&7
      int row = ch >> 3, c16 = ch & 7;
      kPh[p] = *(const half8*)(kbh + (size_t)(m0r + row) * QK_F + c16 * 8);
      kPl[p] = *(const half8*)(kbl + (size_t)(m0r + row) * QK_F + c16 * 8);
    }
  };
  loadK(0);

  float rsum[4][4] = {};
  for (int i = 0; i < 9; ++i){
    // write prefetched K regs to private LDS (rotated, 16-row tile)
    #pragma unroll
    for (int p = 0; p < 2; ++p){
      int ch = p * 64 + lane;
      int row = ch >> 3, c16 = ch & 7;
      *(half8*)(kh + rotIdx(row, c16)) = kPh[p];
      *(half8*)(kl + rotIdx(row, c16)) = kPl[p];
    }
    if (i < 8) loadK(i + 1);          // issue early; retires under compute
    // B frags (compiler inserts lgkmcnt before these reads)
    f32x4 acc[4];
    #pragma unroll
    for (int s = 0; s < 4; ++s) acc[s] = (f32x4){0.f, 0.f, 0.f, 0.f};
    #pragma unroll
    for (int kc = 0; kc < 2; ++kc){
      half8 kb8 = *(half8*)(kh + rotIdx(tx, kc * 4 + hi));
      half8 kl8 = *(half8*)(kl + rotIdx(tx, kc * 4 + hi));
      #pragma unroll
      for (int s = 0; s < 4; ++s){
        acc[s] = MFMA16(qAh[s][kc], kb8, acc[s]);
        acc[s] = MFMA16(qAl[s][kc], kb8, acc[s]);
        acc[s] = MFMA16(qAh[s][kc], kl8, acc[s]);
      }
    }
    float csum = 0.f;
    #pragma unroll
    for (int s = 0; s < 4; ++s)
      #pragma unroll
      for (int rr = 0; rr < 4; ++rr){
        float e = __expf(acc[s][rr] * 0.125f);
        rsum[s][rr] += e;
        csum += e;
      }
    csum += __shfl_xor(csum, 16);
    csum += __shfl_xor(csum, 32);
    if (lane < 16)
      cs_part[((size_t)mb * 9 + nt) * NSEQ + mw0 + i * 16 + tx] = csum;
  }
  // rs reduction (once per block)
  #pragma unroll
  for (int s = 0; s < 4; ++s)
    #pragma unroll
    for (int rr = 0; rr < 4; ++rr){
      float v = rsum[s][rr];
      v += __shfl_xor(v, 1);
      v += __shfl_xor(v, 2);
      v += __shfl_xor(v, 4);
      v += __shfl_xor(v, 8);
      if (tx == 0) rsLds[w][s * 16 + hi * 4 + rr] = v;
    }
  __syncthreads();
  if (t < 64)
    rs[(size_t)mb * NSEQ + n0 + t] = rsLds[0][t] + rsLds[1][t] + rsLds[2][t] + rsLds[3][t];
}

// ---- K2b: reduce 9 col-sum partials -> cs
__global__ __launch_bounds__(256) void k_cs_reduce(const float* __restrict__ cs_part, float* __restrict__ cs){
  int tid = blockIdx.x * 256 + threadIdx.x;
  if (tid >= 2 * BHN * NSEQ) return;
  int mb = tid / NSEQ, m = tid % NSEQ;
  float s = 0.f;
  #pragma unroll
  for (int p = 0; p < 9; ++p)
    s += cs_part[((size_t)mb * 9 + p) * NSEQ + m];
  cs[tid] = s;
}

// ---- K3: apply pass v6 (R14, validated): K register-prefetch; V staged per mt.
__global__ __launch_bounds__(256) void k_apply_mfma(const _Float16* __restrict__ qh, const _Float16* __restrict__ ql,
                                                    const _Float16* __restrict__ vpTh, const _Float16* __restrict__ vpTl,
                                                    const float* __restrict__ rs, const float* __restrict__ cs,
                                                    _Float16* __restrict__ tTh, _Float16* __restrict__ tTl, int map){
  int wg = (blockIdx.x & 7) * 216 + (blockIdx.x >> 3);   // 1728 = 8*216
  int bh = wg / 9, nt = wg % 9;
  int b = bh / 3, h = bh % 3;
  int qi = 1 - map, ki = map;
  int mb = map * BHN + bh;
  const _Float16* qbh = qh + (size_t)((qi * 64 + b) * NSEQ) * QK_F + h * HD;
  const _Float16* qbl = ql + (size_t)((qi * 64 + b) * NSEQ) * QK_F + h * HD;
  const _Float16* kbh = qh + (size_t)((ki * 64 + b) * NSEQ) * QK_F + FEAT + h * HD;
  const _Float16* kbl = ql + (size_t)((ki * 64 + b) * NSEQ) * QK_F + FEAT + h * HD;
  const _Float16* vTh = vpTh + (size_t)mb * 80 * NSEQ;
  const _Float16* vTl = vpTl + (size_t)mb * 80 * NSEQ;
  int n0 = nt * 64;
  __shared__ __align__(16) _Float16 Ash[64][72];
  __shared__ __align__(16) _Float16 Asl[64][72];
  __shared__ __align__(16) _Float16 Vth[80][72];
  __shared__ __align__(16) _Float16 Vtl[80][72];
  __shared__ float cinv[64];
  int t = threadIdx.x;
  int w = t >> 6, lane = t & 63, tx = lane & 15, hi = lane >> 4;

  stage_copy64(qbh + (size_t)n0 * QK_F, QK_F, Ash, t);
  stage_copy64(qbl + (size_t)n0 * QK_F, QK_F, Asl, t);
  __syncthreads();
  half8 qB0h = fragT<72>(Ash, w * 16 + tx, 0 + hi * 4);
  half8 qB1h = fragT<72>(Ash, w * 16 + tx, 32 + hi * 4);
  half8 qB0l = fragT<72>(Asl, w * 16 + tx, 0 + hi * 4);
  half8 qB1l = fragT<72>(Asl, w * 16 + tx, 32 + hi * 4);
  float rinv = 1.0f / rs[(size_t)mb * NSEQ + n0 + w * 16 + tx];

  half8 kPh[2], kPl[2];
  auto loadK = [&](int mt2){
    int m0 = mt2 * 64;
    #pragma unroll
    for (int k2 = 0; k2 < 2; ++k2){
      int idx = t + 256 * k2;
      int row = idx >> 3, c = (idx & 7) << 3;
      kPh[k2] = *(const half8*)(kbh + (size_t)(m0 + row) * QK_F + c);
      kPl[k2] = *(const half8*)(kbl + (size_t)(m0 + row) * QK_F + c);
    }
  };
  loadK(0);

  f32x4 tacc[5];
  #pragma unroll
  for (int et = 0; et < 5; ++et) tacc[et] = (f32x4){0.f, 0.f, 0.f, 0.f};

  for (int mt = 0; mt < 9; ++mt){
    int m0 = mt * 64;
    __syncthreads();
    #pragma unroll
    for (int k2 = 0; k2 < 2; ++k2){
      int idx = t + 256 * k2;
      int row = idx >> 3, c = (idx & 7) << 3;
      half8 vh = kPh[k2], vl = kPl[k2];
      *(half4*)&Ash[row][c]     = (half4){vh[0], vh[1], vh[2], vh[3]};
      *(half4*)&Ash[row][c + 4] = (half4){vh[4], vh[5], vh[6], vh[7]};
      *(half4*)&Asl[row][c]     = (half4){vl[0], vl[1], vl[2], vl[3]};
      *(half4*)&Asl[row][c + 4] = (half4){vl[4], vl[5], vl[6], vl[7]};
    }
    #pragma unroll
    for (int k2 = 0; k2 < 3; ++k2){
      int idx = t + 256 * k2;
      if (idx < 640){
        int row = idx >> 3, c = (idx & 7) << 3;
        half8 v1 = *(const half8*)(vTh + (size_t)row * NSEQ + m0 + c);
        *(half4*)&Vth[row][c]     = (half4){v1[0], v1[1], v1[2], v1[3]};
        *(half4*)&Vth[row][c + 4] = (half4){v1[4], v1[5], v1[6], v1[7]};
        half8 v2 = *(const half8*)(vTl + (size_t)row * NSEQ + m0 + c);
        *(half4*)&Vtl[row][c]     = (half4){v2[0], v2[1], v2[2], v2[3]};
        *(half4*)&Vtl[row][c + 4] = (half4){v2[4], v2[5], v2[6], v2[7]};
      }
    }
    if (t < 64) cinv[t] = 1.0f / cs[(size_t)mb * NSEQ + m0 + t];
    __syncthreads();
    if (mt < 8) loadK(mt + 1);

    f32x4 acc[4];
    #pragma unroll
    for (int s = 0; s < 4; ++s) acc[s] = (f32x4){0.f, 0.f, 0.f, 0.f};
    #pragma unroll
    for (int s = 0; s < 4; ++s){
      half8 kh0 = fragT<72>(Ash, s * 16 + tx, 0 + hi * 4);
      half8 kl0 = fragT<72>(Asl, s * 16 + tx, 0 + hi * 4);
      half8 kh1 = fragT<72>(Ash, s * 16 + tx, 32 + hi * 4);
      half8 kl1 = fragT<72>(Asl, s * 16 + tx, 32 + hi * 4);
      acc[s] = MFMA16(kh0, qB0h, acc[s]);
      acc[s] = MFMA16(kl0, qB0h, acc[s]);
      acc[s] = MFMA16(kh0, qB0l, acc[s]);
      acc[s] = MFMA16(kh1, qB1h, acc[s]);
      acc[s] = MFMA16(kl1, qB1h, acc[s]);
      acc[s] = MFMA16(kh1, qB1l, acc[s]);
    }
    half8 bph[2], bpl[2];
    #pragma unroll
    for (int s = 0; s < 4; ++s){
      #pragma unroll
      for (int rr = 0; rr < 4; ++rr){
        float af = __expf(acc[s][rr] * 0.25f) * rinv * cinv[s * 16 + hi * 4 + rr];
        _Float16 hh = (_Float16)af;
        bph[s >> 1][(s & 1) * 4 + rr] = hh;
        bpl[s >> 1][(s & 1) * 4 + rr] = (_Float16)(af - (float)hh);
      }
    }
    #pragma unroll
    for (int et = 0; et < 5; ++et)
      #pragma unroll
      for (int mc = 0; mc < 2; ++mc){
        half8 vhf = fragT<72>(Vth, et * 16 + tx, mc * 32 + hi * 4);
        half8 vlf = fragT<72>(Vtl, et * 16 + tx, mc * 32 + hi * 4);
        tacc[et] = MFMA16(vhf, bph[mc], tacc[et]);
        tacc[et] = MFMA16(vhf, bpl[mc], tacc[et]);
        tacc[et] = MFMA16(vlf, bph[mc], tacc[et]);
      }
  }
  #pragma unroll
  for (int et = 0; et < 5; ++et)
    #pragma unroll
    for (int rr = 0; rr < 4; ++rr){
      int e = et * 16 + hi * 4 + rr;
      float v = tacc[et][rr];
      _Float16 hh = (_Float16)v;
      size_t o = ((size_t)bh * 80 + e) * NSEQ + n0 + w * 16 + tx;
      tTh[o] = hh;
      tTl[o] = (_Float16)(v - (float)hh);
    }
}

// ---- K4: f = vpT @ t^T' via MFMA (per map, 3 K-parts). featT3[part][k][b]
__global__ __launch_bounds__(256) void k_f_gemm_mfma(const _Float16* __restrict__ vpTh, const _Float16* __restrict__ vpTl,
                                                     const _Float16* __restrict__ tTh, const _Float16* __restrict__ tTl,
                                                     float* __restrict__ featT3, int map){
  int wg = blockIdx.x;                 // 576 = 192 mbL * 3 parts
  int mbL = wg / 3, part = wg % 3;
  int b = mbL / 3, h = mbL % 3;
  __shared__ __align__(16) _Float16 Ah[80][40], Al[80][40], Bh[80][40], Bl[80][40];
  int t = threadIdx.x;
  int w4 = t >> 6, lane = t & 63, tx = lane & 15, hi = lane >> 4;
  const _Float16* Abh = vpTh + (size_t)(map * BHN + mbL) * 80 * NSEQ;
  const _Float16* Abl = vpTl + (size_t)(map * BHN + mbL) * 80 * NSEQ;
  const _Float16* Bbh = tTh + (size_t)mbL * 80 * NSEQ;
  const _Float16* Bbl = tTl + (size_t)mbL * 80 * NSEQ;
  f32x4 acc[7];
  #pragma unroll
  for (int j = 0; j < 7; ++j) acc[j] = (f32x4){0.f, 0.f, 0.f, 0.f};

  for (int kc = part * 6; kc < part * 6 + 6; ++kc){
    int c0 = kc * 32;
    __syncthreads();
    #pragma unroll
    for (int k2 = 0; k2 < 2; ++k2){
      int idx = t + 256 * k2;
      if (idx < 320){
        int row = idx >> 2, cc = (idx & 3) << 3;
        *(half8*)&Ah[row][cc] = *(const half8*)(Abh + (size_t)row * NSEQ + c0 + cc);
        *(half8*)&Al[row][cc] = *(const half8*)(Abl + (size_t)row * NSEQ + c0 + cc);
        *(half8*)&Bh[row][cc] = *(const half8*)(Bbh + (size_t)row * NSEQ + c0 + cc);
        *(half8*)&Bl[row][cc] = *(const half8*)(Bbl + (size_t)row * NSEQ + c0 + cc);
      }
    }
    __syncthreads();
    #pragma unroll
    for (int j = 0; j < 7; ++j){
      int ti = w4 + 4 * j;
      if (ti < 25){
        int db = ti / 5, eb = ti % 5;
        half8 ah = *(const half8*)&Ah[db * 16 + tx][hi * 8];
        half8 al = *(const half8*)&Al[db * 16 + tx][hi * 8];
        half8 bh = *(const half8*)&Bh[eb * 16 + tx][hi * 8];
        half8 bl = *(const half8*)&Bl[eb * 16 + tx][hi * 8];
        acc[j] = MFMA16(ah, bh, acc[j]);
        acc[j] = MFMA16(al, bh, acc[j]);
        acc[j] = MFMA16(ah, bl, acc[j]);
      }
    }
  }
  #pragma unroll
  for (int j = 0; j < 7; ++j){
    int ti = w4 + 4 * j;
    if (ti < 25){
      int db = ti / 5, eb = ti % 5;
      #pragma unroll
      for (int rr = 0; rr < 4; ++rr){
        int d = db * 16 + hi * 4 + rr, e = eb * 16 + tx;
        if (d < VP && e < VP)
          featT3[(size_t)part * 1881600 + (size_t)(map * 14700 + h * 4900 + d * VP + e) * 64 + b] = acc[j][rr];
      }
    }
  }
}

// ---- K4b: reduce 3 featT parts
__global__ __launch_bounds__(256) void k_feat_reduce(const float* __restrict__ featT3, float* __restrict__ featT){
  int gid = blockIdx.x * 256 + threadIdx.x;
  if (gid >= DIMSZ * 64) return;
  featT[gid] = featT3[gid] + featT3[1881600 + gid] + featT3[2 * 1881600 + gid];
}

// ---- K5: projection GEMM (64x64x300 tiles, 784 blocks)
__global__ __launch_bounds__(256) void k_proj_gemm(const float* __restrict__ featT, const float* __restrict__ pw,
                                                   float* __restrict__ p){
  int ot = blockIdx.x & 7;
  int s  = blockIdx.x >> 3;            // 0..97
  int o0 = ot * 64;
  int kbase = s * 300;
  __shared__ __align__(16) float As[20][72];
  __shared__ __align__(16) float Bs[20][72];
  int t = threadIdx.x, tx = t & 15, ty = t >> 4;
  float acc[4][4] = {};
  for (int kt = 0; kt < 15; ++kt){
    int k0 = kbase + kt * 20;
    __syncthreads();
    #pragma unroll
    for (int r = 0; r < 5; ++r){
      int idx = t + 256 * r;             // 1280 = 20*64
      int bb = idx & 63, kk = idx >> 6;
      As[kk][bb] = featT[(size_t)(k0 + kk) * 64 + bb];
      int ko = idx % 20, oo = idx / 20;
      Bs[ko][oo] = pw[(size_t)(o0 + oo) * DIMSZ + k0 + ko];
    }
    __syncthreads();
    #pragma unroll
    for (int k = 0; k < 20; ++k){
      float4 a4 = *(const float4*)&As[k][ty * 4];
      float4 b4 = *(const float4*)&Bs[k][tx * 4];
      float aa[4] = {a4.x, a4.y, a4.z, a4.w};
      float bb[4] = {b4.x, b4.y, b4.z, b4.w};
      #pragma unroll
      for (int i = 0; i < 4; ++i)
        #pragma unroll
        for (int j = 0; j < 4; ++j)
          acc[i][j] += aa[i] * bb[j];
    }
  }
  int slice = s * 8 + ot;
  #pragma unroll
  for (int i = 0; i < 4; ++i){
    float4 st = make_float4(acc[i][0], acc[i][1], acc[i][2], acc[i][3]);
    *(float4*)&p[(size_t)slice * 4096 + (ty * 4 + i) * 64 + tx * 4] = st;
  }
}

// ---- K6: finalize
__global__ __launch_bounds__(256) void k_finalize(const float* __restrict__ p, const float* __restrict__ pb,
                                                  float* __restrict__ out){
  int gid = blockIdx.x * 256 + threadIdx.x;   // 32768 = b*512 + o
  int o = gid & 511, b = gid >> 9;
  int ot = o >> 6, lo = o & 63;
  float s = pb[o];
  for (int s2 = 0; s2 < 98; ++s2)
    s += p[(size_t)(s2 * 8 + ot) * 4096 + b * 64 + lo];
  out[gid] = fmaxf(s, 0.0f);
}

extern "C" void kernel_launch(void* const* d_in, const int* in_sizes, int n_in,
                              void* d_out, int out_size, void* d_ws, size_t ws_size,
                              hipStream_t stream) {
  const float* x1   = (const float*)d_in[0];
  const float* x2   = (const float*)d_in[1];
  const float* lnw  = (const float*)d_in[2];
  const float* lnb  = (const float*)d_in[3];
  const float* qkvw = (const float*)d_in[4];
  const float* pw   = (const float*)d_in[5];
  const float* pb   = (const float*)d_in[6];
  float* out = (float*)d_out;

  float* w = (float*)d_ws;
  float*     mu      = w;                       // 73728
  float*     rstd    = w + 73728;               // 73728
  _Float16*  qh      = (_Float16*)(w + 147456);     // 14155776 f
  _Float16*  ql      = (_Float16*)(w + 14303232);   // 14155776 f
  _Float16*  vpTh    = (_Float16*)(w + 28459008);   // 8847360 f
  _Float16*  vpTl    = (_Float16*)(w + 37306368);   // 8847360 f
  _Float16*  tTh     = (_Float16*)(w + 46153728);   // 4423680 f
  _Float16*  tTl     = (_Float16*)(w + 50577408);   // 4423680 f
  float*     cs_part = w + 55001088;            // 1990656 (aliased by featT later)
  float*     featT   = w + 55001088;            // 1881600 (alias, used after cs_part dead)
  float*     rs      = w + 56991744;            // 221184
  float*     cs      = w + 57212928;            // 221184
  float*     featT3  = w + 57434112;            // 5644800
  float*     p       = w + 57434112;            // 3211264 (alias: featT3 dead after feat_reduce)
  _Float16*  wrh     = (_Float16*)(w + 60645376);   // 147456 halfs (time-disjoint alias)
  _Float16*  wrl     = (_Float16*)(w + 60719104);   // 147456 halfs
  // total 64684544 floats (~259 MB), unchanged

  k_ln_stats<<<384, 192, 0, stream>>>(x1, x2, mu, rstd);
  k_w_repack<<<72, 256, 0, stream>>>(qkvw, wrh, wrl);
  k_qkv_gemm_mfma<<<10368, 256, 0, stream>>>(x1, x2, mu, rstd, lnw, lnb, wrh, wrl, qh, ql, vpTh, vpTl);
  k_pos_fill<<<13824, 256, 0, stream>>>(vpTh, vpTl);
  k_attn_stats_mfma<<<3456, 256, 0, stream>>>(qh, ql, rs, cs_part);
  k_cs_reduce<<<864, 256, 0, stream>>>(cs_part, cs);
  for (int map = 0; map < 2; ++map){
    k_apply_mfma<<<1728, 256, 0, stream>>>(qh, ql, vpTh, vpTl, rs, cs, tTh, tTl, map);
    k_f_gemm_mfma<<<576, 256, 0, stream>>>(vpTh, vpTl, tTh, tTl, featT3, map);
  }
  k_feat_reduce<<<7350, 256, 0, stream>>>(featT3, featT);
  k_proj_gemm<<<784, 256, 0, stream>>>(featT, pw, p);
  k_finalize<<<128, 256, 0, stream>>>(p, pb, out);
}

// Round 16
// 611.977 us; speedup vs baseline: 1.3312x; 1.3312x over previous
//
#include <hip/hip_runtime.h>

#define NSEQ 576
#define CDIM 256
#define HEADS 3
#define HD 64
#define FEAT 192      // HEADS*HD
#define QKVF 576      // 3*FEAT
#define QK_F 384      // stored q,k cols
#define VP 70         // HD+6
#define BHN 192       // 64*3
#define DIMSZ 29400   // 2*3*70*70

typedef __attribute__((ext_vector_type(8))) _Float16 half8;
typedef __attribute__((ext_vector_type(4))) _Float16 half4;
typedef __attribute__((ext_vector_type(4))) float f32x4;

#define MFMA16(A,B,C) __builtin_amdgcn_mfma_f32_16x16x32_f16(A,B,C,0,0,0)

// positional encoding: pos[n] = {py^2, px^2, py*px, py, px, 1}
__device__ __forceinline__ float posval(int n, int pe){
  int yi = n % 24, xi = n / 24;
  float py = (float)yi * (2.0f/23.0f) - 1.0f;
  float px = (float)xi * (2.0f/23.0f) - 1.0f;
  switch(pe){
    case 0: return py*py;
    case 1: return px*px;
    case 2: return py*px;
    case 3: return py;
    case 4: return px;
    default: return 1.0f;
  }
}

// MFMA fragment, k-enum kappa(hi,i) = dbase + (i>>2)*16 + (i&3); LD = row stride
template<int LD>
__device__ __forceinline__ half8 fragT(const _Float16 (*s)[LD], int row, int dbase){
  half4 a = *(const half4*)&s[row][dbase];
  half4 b = *(const half4*)&s[row][dbase + 16];
  return __builtin_shufflevector(a, b, 0, 1, 2, 3, 4, 5, 6, 7);
}

// copy 64 rows x 64 cols of f16 from global (row stride rstr halfs) into LDS [64][72]
__device__ __forceinline__ void stage_copy64(const _Float16* __restrict__ src, int rstr,
                                             _Float16 (*d)[72], int t){
  #pragma unroll
  for (int k2 = 0; k2 < 2; ++k2){
    int idx = t + 256 * k2;               // 512 chunks of 8 halfs
    int row = idx >> 3, c = (idx & 7) << 3;
    half8 v = *(const half8*)(src + (size_t)row * rstr + c);
    *(half4*)&d[row][c]     = (half4){v[0], v[1], v[2], v[3]};
    *(half4*)&d[row][c + 4] = (half4){v[4], v[5], v[6], v[7]};
  }
}

// Rotated 64-col tile addressing (halfs): row stride 64, 16B-chunk rotation.
__device__ __forceinline__ int rotIdx(int row, int c16){
  return row * 64 + ((((c16) + row) & 7) << 3);
}

// ---- K0: LayerNorm stats
__global__ __launch_bounds__(192) void k_ln_stats(const float* __restrict__ x1, const float* __restrict__ x2,
                                                  float* __restrict__ mu, float* __restrict__ rstd){
  int idx = blockIdx.x;                 // 384
  int i2 = idx / 192;
  int rem = idx % 192;
  int b = rem / 3, ng = rem % 3;
  int n = ng * 192 + threadIdx.x;
  const float* x = i2 ? x2 : x1;
  const float* xb = x + (size_t)b * CDIM * NSEQ + n;
  float s = 0.f, sq = 0.f;
  for (int c = 0; c < CDIM; ++c){
    float v = xb[(size_t)c * NSEQ];
    s += v; sq += v * v;
  }
  float m = s * (1.0f/256.0f);
  float var = sq * (1.0f/256.0f) - m * m;
  int o = (i2 * 64 + b) * NSEQ + n;
  mu[o] = m;
  rstd[o] = rsqrtf(var + 1e-5f);
}

// ---- K0b: repack qkv_w into fragment-order split-f16 chunks (R13, validated).
__global__ __launch_bounds__(256) void k_w_repack(const float* __restrict__ qkvw,
                                                  _Float16* __restrict__ wrh, _Float16* __restrict__ wrl){
  int idx = blockIdx.x * 256 + threadIdx.x;   // 18432 chunks
  if (idx >= 18432) return;
  int fi = idx & 63;
  int r = idx >> 6;
  int hi = r & 3; r >>= 2;
  int kc = r & 1; r >>= 1;
  int cb = r & 3; r >>= 2;
  int ft = r;                 // 0..8
  int f = ft * 64 + fi;
  int cbase = cb * 64 + kc * 32 + hi * 4;
  const float* src = qkvw + (size_t)f * CDIM + cbase;
  float4 a = *(const float4*)src;
  float4 b = *(const float4*)(src + 16);
  float vv[8] = {a.x, a.y, a.z, a.w, b.x, b.y, b.z, b.w};
  half8 h, l;
  #pragma unroll
  for (int j = 0; j < 8; ++j){
    _Float16 hh = (_Float16)vv[j];
    h[j] = hh;
    l[j] = (_Float16)(vv[j] - (float)hh);
  }
  *(half8*)(wrh + (size_t)idx * 8) = h;
  *(half8*)(wrl + (size_t)idx * 8) = l;
}

// ---- K1: fused LN + QKV GEMM (R13 version, validated)
__global__ __launch_bounds__(256) void k_qkv_gemm_mfma(const float* __restrict__ x1, const float* __restrict__ x2,
                                                       const float* __restrict__ mu, const float* __restrict__ rstd,
                                                       const float* __restrict__ lnw, const float* __restrict__ lnb,
                                                       const _Float16* __restrict__ wrh, const _Float16* __restrict__ wrl,
                                                       _Float16* __restrict__ qh, _Float16* __restrict__ ql,
                                                       _Float16* __restrict__ vpTh, _Float16* __restrict__ vpTl){
  int wg = (blockIdx.x & 7) * 1296 + (blockIdx.x >> 3);   // 10368 = 8*1296
  int ft = wg % 9;
  int mt = wg / 9;
  int ibn = mt * 64;
  int i2 = ibn / (64 * NSEQ);
  int bn = ibn % (64 * NSEQ);
  int b  = bn / NSEQ;
  int n0 = bn % NSEQ;
  const float* x = i2 ? x2 : x1;
  const float* xb = x + (size_t)b * CDIM * NSEQ + n0;
  __shared__ __align__(16) _Float16 Xh[64][68];
  __shared__ __align__(16) _Float16 Xl[64][68];
  __shared__ float smu[64], srstd[64], slnw[256], slnb[256];
  int t = threadIdx.x;
  int w = t >> 6, lane = t & 63, tx = lane & 15, hi = lane >> 4;
  if (t < 64){ smu[t] = mu[ibn + t]; srstd[t] = rstd[ibn + t]; }
  slnw[t] = lnw[t]; slnb[t] = lnb[t];

  f32x4 acc[4];
  #pragma unroll
  for (int s = 0; s < 4; ++s) acc[s] = (f32x4){0.f, 0.f, 0.f, 0.f};

  int nA = t & 63, cg = t >> 6;
  int lchunk = hi * 64 + w * 16 + tx;
  for (int c0 = 0; c0 < CDIM; c0 += 64){
    int cb = c0 >> 6;
    __syncthreads();
    float mun = smu[nA], rsn = srstd[nA];
    #pragma unroll
    for (int rr = 0; rr < 16; ++rr){
      int c = cg * 16 + rr;
      float v = xb[(size_t)(c0 + c) * NSEQ + nA];
      float xv = (v - mun) * rsn * slnw[c0 + c] + slnb[c0 + c];
      _Float16 hh = (_Float16)xv;
      Xh[nA][c] = hh;
      Xl[nA][c] = (_Float16)(xv - (float)hh);
    }
    __syncthreads();
    #pragma unroll
    for (int kc = 0; kc < 2; ++kc){
      size_t wo = ((size_t)((ft * 4 + cb) * 2 + kc) * 256 + lchunk) * 8;
      half8 wh = *(const half8*)(wrh + wo);
      half8 wl = *(const half8*)(wrl + wo);
      #pragma unroll
      for (int s = 0; s < 4; ++s){
        half8 xh = fragT<68>(Xh, s * 16 + tx, kc * 32 + hi * 4);
        half8 xl = fragT<68>(Xl, s * 16 + tx, kc * 32 + hi * 4);
        acc[s] = MFMA16(xh, wh, acc[s]);
        acc[s] = MFMA16(xl, wh, acc[s]);
        acc[s] = MFMA16(xh, wl, acc[s]);
      }
    }
  }
  if (ft < 6){
    #pragma unroll
    for (int s = 0; s < 4; ++s)
      #pragma unroll
      for (int rr = 0; rr < 4; ++rr){
        float v = acc[s][rr];
        _Float16 hh = (_Float16)v;
        size_t o = (size_t)(ibn + s * 16 + hi * 4 + rr) * QK_F + ft * 64 + w * 16 + tx;
        qh[o] = hh;
        ql[o] = (_Float16)(v - (float)hh);
      }
  } else {
    __syncthreads();
    #pragma unroll
    for (int s = 0; s < 4; ++s)
      #pragma unroll
      for (int rr = 0; rr < 4; ++rr){
        float v = acc[s][rr];
        _Float16 hh = (_Float16)v;
        Xh[s * 16 + hi * 4 + rr][w * 16 + tx] = hh;
        Xl[s * 16 + hi * 4 + rr][w * 16 + tx] = (_Float16)(v - (float)hh);
      }
    __syncthreads();
    int mbg = i2 * 192 + b * 3 + (ft - 6);
    #pragma unroll
    for (int it = 0; it < 16; ++it){
      int d = (t >> 6) + it * 4;
      int n2 = t & 63;
      size_t o = ((size_t)mbg * 80 + d) * NSEQ + n0 + n2;
      vpTh[o] = Xh[n2][d];
      vpTl[o] = Xl[n2][d];
    }
  }
}

// ---- K1b: fill vpT positional rows 64..79 (rows 70..79 zero)
__global__ __launch_bounds__(256) void k_pos_fill(_Float16* __restrict__ vpTh, _Float16* __restrict__ vpTl){
  int idx = blockIdx.x * 256 + threadIdx.x;
  if (idx >= 384 * 16 * NSEQ) return;
  int n = idx % NSEQ;
  int r = idx / NSEQ;
  int row = 64 + (r & 15);
  int mb = r >> 4;
  float v = 0.f;
  int pe = row - 64;
  if (pe < 6) v = posval(n, pe);
  _Float16 hh = (_Float16)v;
  size_t o = ((size_t)mb * 80 + row) * NSEQ + n;
  vpTh[o] = hh;
  vpTl[o] = (_Float16)(v - (float)hh);
}

// ---- K2: attention stats v7b — barrier-free main loop (R15 structure), with
// plain launch_bounds(256) so the allocator targets ~116 VGPR (no spill; the
// R15 regression was the ",4" hint capping VGPR at 64 -> scratch thrash).
__global__ __launch_bounds__(256) void k_attn_stats_mfma(const _Float16* __restrict__ qh, const _Float16* __restrict__ ql,
                                                         float* __restrict__ rs, float* __restrict__ cs_part){
  int wg = (blockIdx.x & 7) * 432 + (blockIdx.x >> 3);   // 3456 = 8*432
  int map = wg / (BHN * 9);
  int r   = wg % (BHN * 9);
  int bh = r / 9, nt = r % 9;
  int b = bh / 3, h = bh % 3;
  int qi = 1 - map, ki = map;
  int mb = map * BHN + bh;
  const _Float16* qbh = qh + (size_t)((qi * 64 + b) * NSEQ) * QK_F + h * HD;
  const _Float16* qbl = ql + (size_t)((qi * 64 + b) * NSEQ) * QK_F + h * HD;
  const _Float16* kbh = qh + (size_t)((ki * 64 + b) * NSEQ) * QK_F + FEAT + h * HD;
  const _Float16* kbl = ql + (size_t)((ki * 64 + b) * NSEQ) * QK_F + FEAT + h * HD;
  int n0 = nt * 64;
  __shared__ __align__(16) _Float16 Sh[4096];    // Q stage, then 4x wave-private K
  __shared__ __align__(16) _Float16 Sl[4096];
  __shared__ float rsLds[4][64];
  int t = threadIdx.x;
  int w = t >> 6, lane = t & 63, tx = lane & 15, hi = lane >> 4;

  // stage Q (rows n0..n0+63) rotated, extract persistent A-frags
  for (int idx = t; idx < 1024; idx += 256){
    int a = idx >> 9, rc = idx & 511, row = rc >> 3, c16 = rc & 7;
    const _Float16* src = a ? qbl : qbh;
    _Float16* dst = a ? Sl : Sh;
    *(half8*)(dst + rotIdx(row, c16)) = *(const half8*)(src + (size_t)(n0 + row) * QK_F + c16 * 8);
  }
  __syncthreads();
  half8 qAh[4][2], qAl[4][2];
  #pragma unroll
  for (int s = 0; s < 4; ++s)
    #pragma unroll
    for (int kc = 0; kc < 2; ++kc){
      qAh[s][kc] = *(half8*)(Sh + rotIdx(s * 16 + tx, kc * 4 + hi));
      qAl[s][kc] = *(half8*)(Sl + rotIdx(s * 16 + tx, kc * 4 + hi));
    }
  __syncthreads();                    // all Q reads done; regions become private

  // wave-private K region (16 rows x 64 cols, rotated within 16-row tile)
  _Float16* kh = Sh + w * 1024;
  _Float16* kl = Sl + w * 1024;
  int mw0 = w * 144;
  half8 kPh[2], kPl[2];
  auto loadK = [&](int i){
    int m0r = mw0 + i * 16;
    #pragma unroll
    for (int p = 0; p < 2; ++p){
      int ch = p * 64 + lane;         // 128 chunks: row = ch>>3, c16 = ch&7
      int row = ch >> 3, c16 = ch & 7;
      kPh[p] = *(const half8*)(kbh + (size_t)(m0r + row) * QK_F + c16 * 8);
      kPl[p] = *(const half8*)(kbl + (size_t)(m0r + row) * QK_F + c16 * 8);
    }
  };
  loadK(0);

  float rsum[4][4] = {};
  for (int i = 0; i < 9; ++i){
    // write prefetched K regs to private LDS (rotated, 16-row tile)
    #pragma unroll
    for (int p = 0; p < 2; ++p){
      int ch = p * 64 + lane;
      int row = ch >> 3, c16 = ch & 7;
      *(half8*)(kh + rotIdx(row, c16)) = kPh[p];
      *(half8*)(kl + rotIdx(row, c16)) = kPl[p];
    }
    if (i < 8) loadK(i + 1);          // issue early; retires under compute
    // B frags (compiler inserts lgkmcnt before these reads)
    f32x4 acc[4];
    #pragma unroll
    for (int s = 0; s < 4; ++s) acc[s] = (f32x4){0.f, 0.f, 0.f, 0.f};
    #pragma unroll
    for (int kc = 0; kc < 2; ++kc){
      half8 kb8 = *(half8*)(kh + rotIdx(tx, kc * 4 + hi));
      half8 kl8 = *(half8*)(kl + rotIdx(tx, kc * 4 + hi));
      #pragma unroll
      for (int s = 0; s < 4; ++s){
        acc[s] = MFMA16(qAh[s][kc], kb8, acc[s]);
        acc[s] = MFMA16(qAl[s][kc], kb8, acc[s]);
        acc[s] = MFMA16(qAh[s][kc], kl8, acc[s]);
      }
    }
    float csum = 0.f;
    #pragma unroll
    for (int s = 0; s < 4; ++s)
      #pragma unroll
      for (int rr = 0; rr < 4; ++rr){
        float e = __expf(acc[s][rr] * 0.125f);
        rsum[s][rr] += e;
        csum += e;
      }
    csum += __shfl_xor(csum, 16);
    csum += __shfl_xor(csum, 32);
    if (lane < 16)
      cs_part[((size_t)mb * 9 + nt) * NSEQ + mw0 + i * 16 + tx] = csum;
  }
  // rs reduction (once per block)
  #pragma unroll
  for (int s = 0; s < 4; ++s)
    #pragma unroll
    for (int rr = 0; rr < 4; ++rr){
      float v = rsum[s][rr];
      v += __shfl_xor(v, 1);
      v += __shfl_xor(v, 2);
      v += __shfl_xor(v, 4);
      v += __shfl_xor(v, 8);
      if (tx == 0) rsLds[w][s * 16 + hi * 4 + rr] = v;
    }
  __syncthreads();
  if (t < 64)
    rs[(size_t)mb * NSEQ + n0 + t] = rsLds[0][t] + rsLds[1][t] + rsLds[2][t] + rsLds[3][t];
}

// ---- K2b: reduce 9 col-sum partials -> cs
__global__ __launch_bounds__(256) void k_cs_reduce(const float* __restrict__ cs_part, float* __restrict__ cs){
  int tid = blockIdx.x * 256 + threadIdx.x;
  if (tid >= 2 * BHN * NSEQ) return;
  int mb = tid / NSEQ, m = tid % NSEQ;
  float s = 0.f;
  #pragma unroll
  for (int p = 0; p < 9; ++p)
    s += cs_part[((size_t)mb * 9 + p) * NSEQ + m];
  cs[tid] = s;
}

// ---- K3: apply pass v6 (R14, validated): K register-prefetch; V staged per mt.
__global__ __launch_bounds__(256) void k_apply_mfma(const _Float16* __restrict__ qh, const _Float16* __restrict__ ql,
                                                    const _Float16* __restrict__ vpTh, const _Float16* __restrict__ vpTl,
                                                    const float* __restrict__ rs, const float* __restrict__ cs,
                                                    _Float16* __restrict__ tTh, _Float16* __restrict__ tTl, int map){
  int wg = (blockIdx.x & 7) * 216 + (blockIdx.x >> 3);   // 1728 = 8*216
  int bh = wg / 9, nt = wg % 9;
  int b = bh / 3, h = bh % 3;
  int qi = 1 - map, ki = map;
  int mb = map * BHN + bh;
  const _Float16* qbh = qh + (size_t)((qi * 64 + b) * NSEQ) * QK_F + h * HD;
  const _Float16* qbl = ql + (size_t)((qi * 64 + b) * NSEQ) * QK_F + h * HD;
  const _Float16* kbh = qh + (size_t)((ki * 64 + b) * NSEQ) * QK_F + FEAT + h * HD;
  const _Float16* kbl = ql + (size_t)((ki * 64 + b) * NSEQ) * QK_F + FEAT + h * HD;
  const _Float16* vTh = vpTh + (size_t)mb * 80 * NSEQ;
  const _Float16* vTl = vpTl + (size_t)mb * 80 * NSEQ;
  int n0 = nt * 64;
  __shared__ __align__(16) _Float16 Ash[64][72];
  __shared__ __align__(16) _Float16 Asl[64][72];
  __shared__ __align__(16) _Float16 Vth[80][72];
  __shared__ __align__(16) _Float16 Vtl[80][72];
  __shared__ float cinv[64];
  int t = threadIdx.x;
  int w = t >> 6, lane = t & 63, tx = lane & 15, hi = lane >> 4;

  stage_copy64(qbh + (size_t)n0 * QK_F, QK_F, Ash, t);
  stage_copy64(qbl + (size_t)n0 * QK_F, QK_F, Asl, t);
  __syncthreads();
  half8 qB0h = fragT<72>(Ash, w * 16 + tx, 0 + hi * 4);
  half8 qB1h = fragT<72>(Ash, w * 16 + tx, 32 + hi * 4);
  half8 qB0l = fragT<72>(Asl, w * 16 + tx, 0 + hi * 4);
  half8 qB1l = fragT<72>(Asl, w * 16 + tx, 32 + hi * 4);
  float rinv = 1.0f / rs[(size_t)mb * NSEQ + n0 + w * 16 + tx];

  half8 kPh[2], kPl[2];
  auto loadK = [&](int mt2){
    int m0 = mt2 * 64;
    #pragma unroll
    for (int k2 = 0; k2 < 2; ++k2){
      int idx = t + 256 * k2;
      int row = idx >> 3, c = (idx & 7) << 3;
      kPh[k2] = *(const half8*)(kbh + (size_t)(m0 + row) * QK_F + c);
      kPl[k2] = *(const half8*)(kbl + (size_t)(m0 + row) * QK_F + c);
    }
  };
  loadK(0);

  f32x4 tacc[5];
  #pragma unroll
  for (int et = 0; et < 5; ++et) tacc[et] = (f32x4){0.f, 0.f, 0.f, 0.f};

  for (int mt = 0; mt < 9; ++mt){
    int m0 = mt * 64;
    __syncthreads();
    #pragma unroll
    for (int k2 = 0; k2 < 2; ++k2){
      int idx = t + 256 * k2;
      int row = idx >> 3, c = (idx & 7) << 3;
      half8 vh = kPh[k2], vl = kPl[k2];
      *(half4*)&Ash[row][c]     = (half4){vh[0], vh[1], vh[2], vh[3]};
      *(half4*)&Ash[row][c + 4] = (half4){vh[4], vh[5], vh[6], vh[7]};
      *(half4*)&Asl[row][c]     = (half4){vl[0], vl[1], vl[2], vl[3]};
      *(half4*)&Asl[row][c + 4] = (half4){vl[4], vl[5], vl[6], vl[7]};
    }
    #pragma unroll
    for (int k2 = 0; k2 < 3; ++k2){
      int idx = t + 256 * k2;
      if (idx < 640){
        int row = idx >> 3, c = (idx & 7) << 3;
        half8 v1 = *(const half8*)(vTh + (size_t)row * NSEQ + m0 + c);
        *(half4*)&Vth[row][c]     = (half4){v1[0], v1[1], v1[2], v1[3]};
        *(half4*)&Vth[row][c + 4] = (half4){v1[4], v1[5], v1[6], v1[7]};
        half8 v2 = *(const half8*)(vTl + (size_t)row * NSEQ + m0 + c);
        *(half4*)&Vtl[row][c]     = (half4){v2[0], v2[1], v2[2], v2[3]};
        *(half4*)&Vtl[row][c + 4] = (half4){v2[4], v2[5], v2[6], v2[7]};
      }
    }
    if (t < 64) cinv[t] = 1.0f / cs[(size_t)mb * NSEQ + m0 + t];
    __syncthreads();
    if (mt < 8) loadK(mt + 1);

    f32x4 acc[4];
    #pragma unroll
    for (int s = 0; s < 4; ++s) acc[s] = (f32x4){0.f, 0.f, 0.f, 0.f};
    #pragma unroll
    for (int s = 0; s < 4; ++s){
      half8 kh0 = fragT<72>(Ash, s * 16 + tx, 0 + hi * 4);
      half8 kl0 = fragT<72>(Asl, s * 16 + tx, 0 + hi * 4);
      half8 kh1 = fragT<72>(Ash, s * 16 + tx, 32 + hi * 4);
      half8 kl1 = fragT<72>(Asl, s * 16 + tx, 32 + hi * 4);
      acc[s] = MFMA16(kh0, qB0h, acc[s]);
      acc[s] = MFMA16(kl0, qB0h, acc[s]);
      acc[s] = MFMA16(kh0, qB0l, acc[s]);
      acc[s] = MFMA16(kh1, qB1h, acc[s]);
      acc[s] = MFMA16(kl1, qB1h, acc[s]);
      acc[s] = MFMA16(kh1, qB1l, acc[s]);
    }
    half8 bph[2], bpl[2];
    #pragma unroll
    for (int s = 0; s < 4; ++s){
      #pragma unroll
      for (int rr = 0; rr < 4; ++rr){
        float af = __expf(acc[s][rr] * 0.25f) * rinv * cinv[s * 16 + hi * 4 + rr];
        _Float16 hh = (_Float16)af;
        bph[s >> 1][(s & 1) * 4 + rr] = hh;
        bpl[s >> 1][(s & 1) * 4 + rr] = (_Float16)(af - (float)hh);
      }
    }
    #pragma unroll
    for (int et = 0; et < 5; ++et)
      #pragma unroll
      for (int mc = 0; mc < 2; ++mc){
        half8 vhf = fragT<72>(Vth, et * 16 + tx, mc * 32 + hi * 4);
        half8 vlf = fragT<72>(Vtl, et * 16 + tx, mc * 32 + hi * 4);
        tacc[et] = MFMA16(vhf, bph[mc], tacc[et]);
        tacc[et] = MFMA16(vhf, bpl[mc], tacc[et]);
        tacc[et] = MFMA16(vlf, bph[mc], tacc[et]);
      }
  }
  #pragma unroll
  for (int et = 0; et < 5; ++et)
    #pragma unroll
    for (int rr = 0; rr < 4; ++rr){
      int e = et * 16 + hi * 4 + rr;
      float v = tacc[et][rr];
      _Float16 hh = (_Float16)v;
      size_t o = ((size_t)bh * 80 + e) * NSEQ + n0 + w * 16 + tx;
      tTh[o] = hh;
      tTl[o] = (_Float16)(v - (float)hh);
    }
}

// ---- K4: f = vpT @ t^T' via MFMA (per map, 3 K-parts). featT3[part][k][b]
__global__ __launch_bounds__(256) void k_f_gemm_mfma(const _Float16* __restrict__ vpTh, const _Float16* __restrict__ vpTl,
                                                     const _Float16* __restrict__ tTh, const _Float16* __restrict__ tTl,
                                                     float* __restrict__ featT3, int map){
  int wg = blockIdx.x;                 // 576 = 192 mbL * 3 parts
  int mbL = wg / 3, part = wg % 3;
  int b = mbL / 3, h = mbL % 3;
  __shared__ __align__(16) _Float16 Ah[80][40], Al[80][40], Bh[80][40], Bl[80][40];
  int t = threadIdx.x;
  int w4 = t >> 6, lane = t & 63, tx = lane & 15, hi = lane >> 4;
  const _Float16* Abh = vpTh + (size_t)(map * BHN + mbL) * 80 * NSEQ;
  const _Float16* Abl = vpTl + (size_t)(map * BHN + mbL) * 80 * NSEQ;
  const _Float16* Bbh = tTh + (size_t)mbL * 80 * NSEQ;
  const _Float16* Bbl = tTl + (size_t)mbL * 80 * NSEQ;
  f32x4 acc[7];
  #pragma unroll
  for (int j = 0; j < 7; ++j) acc[j] = (f32x4){0.f, 0.f, 0.f, 0.f};

  for (int kc = part * 6; kc < part * 6 + 6; ++kc){
    int c0 = kc * 32;
    __syncthreads();
    #pragma unroll
    for (int k2 = 0; k2 < 2; ++k2){
      int idx = t + 256 * k2;
      if (idx < 320){
        int row = idx >> 2, cc = (idx & 3) << 3;
        *(half8*)&Ah[row][cc] = *(const half8*)(Abh + (size_t)row * NSEQ + c0 + cc);
        *(half8*)&Al[row][cc] = *(const half8*)(Abl + (size_t)row * NSEQ + c0 + cc);
        *(half8*)&Bh[row][cc] = *(const half8*)(Bbh + (size_t)row * NSEQ + c0 + cc);
        *(half8*)&Bl[row][cc] = *(const half8*)(Bbl + (size_t)row * NSEQ + c0 + cc);
      }
    }
    __syncthreads();
    #pragma unroll
    for (int j = 0; j < 7; ++j){
      int ti = w4 + 4 * j;
      if (ti < 25){
        int db = ti / 5, eb = ti % 5;
        half8 ah = *(const half8*)&Ah[db * 16 + tx][hi * 8];
        half8 al = *(const half8*)&Al[db * 16 + tx][hi * 8];
        half8 bh = *(const half8*)&Bh[eb * 16 + tx][hi * 8];
        half8 bl = *(const half8*)&Bl[eb * 16 + tx][hi * 8];
        acc[j] = MFMA16(ah, bh, acc[j]);
        acc[j] = MFMA16(al, bh, acc[j]);
        acc[j] = MFMA16(ah, bl, acc[j]);
      }
    }
  }
  #pragma unroll
  for (int j = 0; j < 7; ++j){
    int ti = w4 + 4 * j;
    if (ti < 25){
      int db = ti / 5, eb = ti % 5;
      #pragma unroll
      for (int rr = 0; rr < 4; ++rr){
        int d = db * 16 + hi * 4 + rr, e = eb * 16 + tx;
        if (d < VP && e < VP)
          featT3[(size_t)part * 1881600 + (size_t)(map * 14700 + h * 4900 + d * VP + e) * 64 + b] = acc[j][rr];
      }
    }
  }
}

// ---- K4b: reduce 3 featT parts
__global__ __launch_bounds__(256) void k_feat_reduce(const float* __restrict__ featT3, float* __restrict__ featT){
  int gid = blockIdx.x * 256 + threadIdx.x;
  if (gid >= DIMSZ * 64) return;
  featT[gid] = featT3[gid] + featT3[1881600 + gid] + featT3[2 * 1881600 + gid];
}

// ---- K5: projection GEMM (64x64x300 tiles, 784 blocks)
__global__ __launch_bounds__(256) void k_proj_gemm(const float* __restrict__ featT, const float* __restrict__ pw,
                                                   float* __restrict__ p){
  int ot = blockIdx.x & 7;
  int s  = blockIdx.x >> 3;            // 0..97
  int o0 = ot * 64;
  int kbase = s * 300;
  __shared__ __align__(16) float As[20][72];
  __shared__ __align__(16) float Bs[20][72];
  int t = threadIdx.x, tx = t & 15, ty = t >> 4;
  float acc[4][4] = {};
  for (int kt = 0; kt < 15; ++kt){
    int k0 = kbase + kt * 20;
    __syncthreads();
    #pragma unroll
    for (int r = 0; r < 5; ++r){
      int idx = t + 256 * r;             // 1280 = 20*64
      int bb = idx & 63, kk = idx >> 6;
      As[kk][bb] = featT[(size_t)(k0 + kk) * 64 + bb];
      int ko = idx % 20, oo = idx / 20;
      Bs[ko][oo] = pw[(size_t)(o0 + oo) * DIMSZ + k0 + ko];
    }
    __syncthreads();
    #pragma unroll
    for (int k = 0; k < 20; ++k){
      float4 a4 = *(const float4*)&As[k][ty * 4];
      float4 b4 = *(const float4*)&Bs[k][tx * 4];
      float aa[4] = {a4.x, a4.y, a4.z, a4.w};
      float bb[4] = {b4.x, b4.y, b4.z, b4.w};
      #pragma unroll
      for (int i = 0; i < 4; ++i)
        #pragma unroll
        for (int j = 0; j < 4; ++j)
          acc[i][j] += aa[i] * bb[j];
    }
  }
  int slice = s * 8 + ot;
  #pragma unroll
  for (int i = 0; i < 4; ++i){
    float4 st = make_float4(acc[i][0], acc[i][1], acc[i][2], acc[i][3]);
    *(float4*)&p[(size_t)slice * 4096 + (ty * 4 + i) * 64 + tx * 4] = st;
  }
}

// ---- K6: finalize
__global__ __launch_bounds__(256) void k_finalize(const float* __restrict__ p, const float* __restrict__ pb,
                                                  float* __restrict__ out){
  int gid = blockIdx.x * 256 + threadIdx.x;   // 32768 = b*512 + o
  int o = gid & 511, b = gid >> 9;
  int ot = o >> 6, lo = o & 63;
  float s = pb[o];
  for (int s2 = 0; s2 < 98; ++s2)
    s += p[(size_t)(s2 * 8 + ot) * 4096 + b * 64 + lo];
  out[gid] = fmaxf(s, 0.0f);
}

extern "C" void kernel_launch(void* const* d_in, const int* in_sizes, int n_in,
                              void* d_out, int out_size, void* d_ws, size_t ws_size,
                              hipStream_t stream) {
  const float* x1   = (const float*)d_in[0];
  const float* x2   = (const float*)d_in[1];
  const float* lnw  = (const float*)d_in[2];
  const float* lnb  = (const float*)d_in[3];
  const float* qkvw = (const float*)d_in[4];
  const float* pw   = (const float*)d_in[5];
  const float* pb   = (const float*)d_in[6];
  float* out = (float*)d_out;

  float* w = (float*)d_ws;
  float*     mu      = w;                       // 73728
  float*     rstd    = w + 73728;               // 73728
  _Float16*  qh      = (_Float16*)(w + 147456);     // 14155776 f
  _Float16*  ql      = (_Float16*)(w + 14303232);   // 14155776 f
  _Float16*  vpTh    = (_Float16*)(w + 28459008);   // 8847360 f
  _Float16*  vpTl    = (_Float16*)(w + 37306368);   // 8847360 f
  _Float16*  tTh     = (_Float16*)(w + 46153728);   // 4423680 f
  _Float16*  tTl     = (_Float16*)(w + 50577408);   // 4423680 f
  float*     cs_part = w + 55001088;            // 1990656 (aliased by featT later)
  float*     featT   = w + 55001088;            // 1881600 (alias, used after cs_part dead)
  float*     rs      = w + 56991744;            // 221184
  float*     cs      = w + 57212928;            // 221184
  float*     featT3  = w + 57434112;            // 5644800
  float*     p       = w + 57434112;            // 3211264 (alias: featT3 dead after feat_reduce)
  _Float16*  wrh     = (_Float16*)(w + 60645376);   // 147456 halfs (time-disjoint alias)
  _Float16*  wrl     = (_Float16*)(w + 60719104);   // 147456 halfs
  // total 64684544 floats (~259 MB), unchanged

  k_ln_stats<<<384, 192, 0, stream>>>(x1, x2, mu, rstd);
  k_w_repack<<<72, 256, 0, stream>>>(qkvw, wrh, wrl);
  k_qkv_gemm_mfma<<<10368, 256, 0, stream>>>(x1, x2, mu, rstd, lnw, lnb, wrh, wrl, qh, ql, vpTh, vpTl);
  k_pos_fill<<<13824, 256, 0, stream>>>(vpTh, vpTl);
  k_attn_stats_mfma<<<3456, 256, 0, stream>>>(qh, ql, rs, cs_part);
  k_cs_reduce<<<864, 256, 0, stream>>>(cs_part, cs);
  for (int map = 0; map < 2; ++map){
    k_apply_mfma<<<1728, 256, 0, stream>>>(qh, ql, vpTh, vpTl, rs, cs, tTh, tTl, map);
    k_f_gemm_mfma<<<576, 256, 0, stream>>>(vpTh, vpTl, tTh, tTl, featT3, map);
  }
  k_feat_reduce<<<7350, 256, 0, stream>>>(featT3, featT);
  k_proj_gemm<<<784, 256, 0, stream>>>(featT, pw, p);
  k_finalize<<<128, 256, 0, stream>>>(p, pb, out);
}